// Round 4
// baseline (20.468 us; speedup 1.0000x reference)
//
#include <hip/hip_runtime.h>
#include <hip/hip_bf16.h>

#define NN 6400   // total nodes
#define NG 200    // nodes per graph
#define NB 32     // graphs
#define FF 128    // F_in == F_out

typedef __attribute__((ext_vector_type(8))) short s8v;  // 8 x bf16 (4 VGPRs)
typedef __attribute__((ext_vector_type(4))) float f4v;  // MFMA accumulator

__device__ __forceinline__ short f2bf(float x) {
  unsigned u = __float_as_uint(x);
  u += 0x7FFFu + ((u >> 16) & 1u);   // RNE
  return (short)(u >> 16);
}

// supp fragment layout: [b][kc=7][nt=8][lane=64][e=8] bf16 (K padded to 224)
__device__ __forceinline__ size_t supp_elem(int b, int kloc, int n) {
  return ((((size_t)b * 7 + (kloc >> 5)) * 8 + (n >> 4)) * 64
          + (n & 15) + ((kloc >> 3) & 3) * 16) * 8 + (kloc & 7);
}

// M fragment layout: [b*8+slab][mt=2][kc=7][lane=64][e=8] bf16
#define SUPP_SHORTS  (32 * 7 * 8 * 512)          // 917,504 shorts
#define MF_PER_SLAB  (2 * 7 * 64 * 8)            // 7,168 shorts

// ---------------------------------------------------------------------------
// K1, 488 blocks:
//   0..199  : support = feat @ W (MFMA) -> bf16 B-frags in ws
//   200..231: zero-fill K-pad (k=200..223) supp fragment slots for graph b
//   232..487: build M = sigmoid(adj_bb)*(0.5(R+R^T)+I) as A-frags -> ws
// ---------------------------------------------------------------------------
__global__ __launch_bounds__(256) void prep_kernel(
    const float* __restrict__ feat, const float* __restrict__ weight,
    const float* __restrict__ rew, const float* __restrict__ adj,
    short* __restrict__ supp, short* __restrict__ mfrag)
{
  __shared__ char lds_raw[32768];
  const int t = threadIdx.x;
  const int bid = blockIdx.x;

  if (bid < 200) {                       // ======== support build ========
    s8v* sW = (s8v*)lds_raw;             // W B-frags [kc=4][nt=8][lane=64]

    for (int p = 0; p < 8; ++p) {
      const int idx = t + p * 256;
      const int n = idx & 127, kg = idx >> 7;
      s8v v;
#pragma unroll
      for (int e = 0; e < 8; ++e)
        v[e] = f2bf(weight[(kg * 8 + e) * FF + n]);
      sW[((kg >> 2) * 8 + (n >> 4)) * 64 + (n & 15) + (kg & 3) * 16] = v;
    }
    __syncthreads();

    const int w = t >> 6, l = t & 63;
    const int mt = w >> 1, nh = w & 1;
    const int arow = bid * 32 + mt * 16 + (l & 15);
    const int klane = (l >> 4) * 8;

    f4v acc0 = {0.f,0.f,0.f,0.f}, acc1 = acc0, acc2 = acc0, acc3 = acc0;
#pragma unroll
    for (int kc = 0; kc < 4; ++kc) {
      const float* fp = feat + (size_t)arow * FF + kc * 32 + klane;
      const float4 fa = *(const float4*)fp;
      const float4 fb = *(const float4*)(fp + 4);
      s8v af;
      af[0]=f2bf(fa.x); af[1]=f2bf(fa.y); af[2]=f2bf(fa.z); af[3]=f2bf(fa.w);
      af[4]=f2bf(fb.x); af[5]=f2bf(fb.y); af[6]=f2bf(fb.z); af[7]=f2bf(fb.w);
      acc0 = __builtin_amdgcn_mfma_f32_16x16x32_bf16(af, sW[(kc*8 + nh*4 + 0)*64 + l], acc0, 0,0,0);
      acc1 = __builtin_amdgcn_mfma_f32_16x16x32_bf16(af, sW[(kc*8 + nh*4 + 1)*64 + l], acc1, 0,0,0);
      acc2 = __builtin_amdgcn_mfma_f32_16x16x32_bf16(af, sW[(kc*8 + nh*4 + 2)*64 + l], acc2, 0,0,0);
      acc3 = __builtin_amdgcn_mfma_f32_16x16x32_bf16(af, sW[(kc*8 + nh*4 + 3)*64 + l], acc3, 0,0,0);
    }

#pragma unroll
    for (int reg = 0; reg < 4; ++reg) {
      const int rr = bid * 32 + mt * 16 + (l >> 4) * 4 + reg;
      const unsigned bb = (unsigned)rr / 200u;
      const int kloc = rr - (int)bb * 200;
      const int n0 = nh * 64 + (l & 15);
      supp[supp_elem(bb, kloc, n0)]      = f2bf(acc0[reg]);
      supp[supp_elem(bb, kloc, n0 + 16)] = f2bf(acc1[reg]);
      supp[supp_elem(bb, kloc, n0 + 32)] = f2bf(acc2[reg]);
      supp[supp_elem(bb, kloc, n0 + 48)] = f2bf(acc3[reg]);
    }

  } else if (bid < 232) {                // ======== K-pad zero-fill ========
    const int b = bid - 200;
    const size_t base = (((size_t)b * 7 + 6) * 8) * 512;  // [b][kc=6][0][0][0]
    for (int q = t; q < 1536; q += 256) {
      const int nt = q / 192, p = q - nt * 192;
      unsigned* dst = (unsigned*)(supp + base + (size_t)nt * 512 + 128) + p;
      *dst = 0u;
    }

  } else {                               // ======== M-fragment build ========
    float* sRT = (float*)lds_raw;        // [32][200] rew transpose slice
    const int m = bid - 232;
    const int b = m >> 3, slab = m & 7;
    const int i0 = slab * 25;

    // stage sRT[c][j] = rew[j][i0+c] (coalesced within 800 B rows via j-runs)
    for (int p = 0; p < 25; ++p) {
      const int idx = t + p * 256;       // < 6400
      const int c = idx / 200, j = idx - c * 200;
      float v = 0.f;
      if (i0 + c < 200) v = rew[j * NG + i0 + c];
      sRT[c * 200 + j] = v;
    }
    __syncthreads();

    short* mf = mfrag + (size_t)m * MF_PER_SLAB;
#pragma unroll
    for (int p = 0; p < 4; ++p) {
      const int idx = t + p * 256;
      if (idx < 896) {                   // 32 rows x 28 j-groups
        const int i = idx / 28, jg = idx - i * 28;
        const int gi = i0 + i;
        s8v v = {0,0,0,0,0,0,0,0};
        if (jg < 25 && gi < 200) {
          const float* ap = adj + ((size_t)(b * NG + gi) * NN + b * NG + jg * 8);
          const float4 a0 = *(const float4*)ap;
          const float4 a1 = *(const float4*)(ap + 4);
          const float* rp = rew + gi * NG + jg * 8;
          const float4 r0 = *(const float4*)rp;
          const float4 r1 = *(const float4*)(rp + 4);
          const float4 t0 = *(const float4*)&sRT[i * 200 + jg * 8];
          const float4 t1 = *(const float4*)&sRT[i * 200 + jg * 8 + 4];
          const int jd = gi - jg * 8;    // diag when jd == e
          v[0] = f2bf((0.5f*(r0.x+t0.x) + (jd==0)) * __builtin_amdgcn_rcpf(1.f + __expf(-a0.x)));
          v[1] = f2bf((0.5f*(r0.y+t0.y) + (jd==1)) * __builtin_amdgcn_rcpf(1.f + __expf(-a0.y)));
          v[2] = f2bf((0.5f*(r0.z+t0.z) + (jd==2)) * __builtin_amdgcn_rcpf(1.f + __expf(-a0.z)));
          v[3] = f2bf((0.5f*(r0.w+t0.w) + (jd==3)) * __builtin_amdgcn_rcpf(1.f + __expf(-a0.w)));
          v[4] = f2bf((0.5f*(r1.x+t1.x) + (jd==4)) * __builtin_amdgcn_rcpf(1.f + __expf(-a1.x)));
          v[5] = f2bf((0.5f*(r1.y+t1.y) + (jd==5)) * __builtin_amdgcn_rcpf(1.f + __expf(-a1.y)));
          v[6] = f2bf((0.5f*(r1.z+t1.z) + (jd==6)) * __builtin_amdgcn_rcpf(1.f + __expf(-a1.z)));
          v[7] = f2bf((0.5f*(r1.w+t1.w) + (jd==7)) * __builtin_amdgcn_rcpf(1.f + __expf(-a1.w)));
        }
        const int gran = ((i >> 4) * 7 + (jg >> 2)) * 64 + (i & 15) + (jg & 3) * 16;
        *(s8v*)(mf + (size_t)gran * 8) = v;
      }
    }
  }
}

// ---------------------------------------------------------------------------
// K2, 256 blocks: pure MFMA. out_b slab = M_frags @ supp_frags.
// bid -> (b = bid>>3, slab = bid&7) so bid%8 == slab == XCD of the K1 writer.
// ---------------------------------------------------------------------------
__global__ __launch_bounds__(256) void gemm_kernel(
    const short* __restrict__ mfrag, const short* __restrict__ supp,
    float* __restrict__ out)
{
  const int t = threadIdx.x;
  const int bid = blockIdx.x;
  const int b = bid >> 3, slab = bid & 7;
  const int i0 = slab * 25;

  const int w = t >> 6, l = t & 63;
  const int mt = w >> 1, nh = w & 1;

  const s8v* am = (const s8v*)(mfrag + (size_t)bid * MF_PER_SLAB) + (mt * 7) * 64 + l;
  const s8v* sb = (const s8v*)supp + (size_t)b * 7 * 8 * 64 + (nh * 4) * 64 + l;

  f4v acc0 = {0.f,0.f,0.f,0.f}, acc1 = acc0, acc2 = acc0, acc3 = acc0;
#pragma unroll
  for (int kc = 0; kc < 7; ++kc) {
    const s8v af = am[kc * 64];
    acc0 = __builtin_amdgcn_mfma_f32_16x16x32_bf16(af, sb[(kc*8 + 0)*64], acc0, 0,0,0);
    acc1 = __builtin_amdgcn_mfma_f32_16x16x32_bf16(af, sb[(kc*8 + 1)*64], acc1, 0,0,0);
    acc2 = __builtin_amdgcn_mfma_f32_16x16x32_bf16(af, sb[(kc*8 + 2)*64], acc2, 0,0,0);
    acc3 = __builtin_amdgcn_mfma_f32_16x16x32_bf16(af, sb[(kc*8 + 3)*64], acc3, 0,0,0);
  }

#pragma unroll
  for (int reg = 0; reg < 4; ++reg) {
    const int rl = mt * 16 + (l >> 4) * 4 + reg;
    if (rl < 25) {
      const size_t o = (size_t)(b * NG + i0 + rl) * FF + nh * 64 + (l & 15);
      out[o]      = acc0[reg];
      out[o + 16] = acc1[reg];
      out[o + 32] = acc2[reg];
      out[o + 48] = acc3[reg];
    }
  }
}

// ---------------------------------------------------------------------------
extern "C" void kernel_launch(void* const* d_in, const int* in_sizes, int n_in,
                              void* d_out, int out_size, void* d_ws, size_t ws_size,
                              hipStream_t stream)
{
  const float* adj    = (const float*)d_in[0];  // [6400, 6400]
  const float* feat   = (const float*)d_in[1];  // [6400, 128]
  const float* weight = (const float*)d_in[2];  // [128, 128]
  const float* rew    = (const float*)d_in[3];  // [200, 200]
  float*       out    = (float*)d_out;          // [6400, 128]

  short* supp  = (short*)d_ws;                  // 1,835,008 B
  short* mfrag = supp + SUPP_SHORTS;            // 3,670,016 B

  prep_kernel<<<488, 256, 0, stream>>>(feat, weight, rew, adj, supp, mfrag);
  gemm_kernel<<<256, 256, 0, stream>>>(mfrag, supp, out);
}